// Round 4
// baseline (485.974 us; speedup 1.0000x reference)
//
#include <hip/hip_runtime.h>

typedef __attribute__((ext_vector_type(8))) short short8;
typedef __attribute__((ext_vector_type(4))) float f32x4;

__device__ __forceinline__ float bf2f(unsigned short u){
  return __uint_as_float(((unsigned int)u) << 16);
}
__device__ __forceinline__ unsigned short f2bf(float f){
  unsigned int u = __float_as_uint(f);
  u += 0x7fffu + ((u >> 16) & 1u);   // RNE
  return (unsigned short)(u >> 16);
}
// dtype-dispatching scalar load: isF32 ? f32[i] : bf16[i]
__device__ __forceinline__ float ldf(const void* p, long i, int isF32){
  return isF32 ? ((const float*)p)[i] : bf2f(((const unsigned short*)p)[i]);
}

// ---- detect input dtype: bf16 (flag=0) vs f32 (flag=1) ----
__global__ void detect(const unsigned short* __restrict__ x, int* __restrict__ flag){
  __shared__ int s;
  if (threadIdx.x == 0) s = 0;
  __syncthreads();
  int bad = 0;
  for (int i = threadIdx.x; i < 2048; i += 256){
    unsigned int e = ((unsigned int)x[2 * i] >> 7) & 0xffu;
    if (e >= 0xF0u) bad = 1;
  }
  if (bad) atomicOr(&s, 1);
  __syncthreads();
  if (threadIdx.x == 0) *flag = s;
}

// ---- transpose W [K][128] -> WT [128][K], output canonical bf16 ----
__global__ void wtrans(const void* __restrict__ W, unsigned short* __restrict__ WT,
                       int K, const int* __restrict__ flag){
  int isF32 = *flag;
  int idx = blockIdx.x * 256 + threadIdx.x;
  if (idx >= K * 128) return;
  int n = idx / K, k = idx - n * K;
  WT[idx] = f2bf(ldf(W, (long)k * 128 + n, isF32));
}

// ---- row_ptr from sorted rows: rs[r] = first edge with row >= r ----
__global__ void rowptr_k(const int* __restrict__ rows, int* __restrict__ rs,
                         int E, int N){
  int e = blockIdx.x * 256 + threadIdx.x;
  if (e >= E) return;
  if (e == 0){
    for (int r = 0; r <= rows[0]; ++r) rs[r] = 0;
  } else {
    int a = rows[e - 1], b = rows[e];
    for (int r = a + 1; r <= b; ++r) rs[r] = e;
  }
  if (e == E - 1){
    for (int r = rows[E - 1] + 1; r <= N; ++r) rs[r] = E;
  }
}

// ---- fused dual GEMM: z = A@W0 + b0, y1 = A@W1 (K=256), bf16 out ----
// KB=64, both B tiles in LDS (36.9 KB). A fragments loaded direct (per-row).
__global__ __launch_bounds__(256) void gemm_dual(
    const void* __restrict__ A,
    const unsigned short* __restrict__ WT0,  // [128][256] bf16
    const unsigned short* __restrict__ WT1,  // [128][256] bf16
    const void* __restrict__ bias0,
    unsigned short* __restrict__ out0,       // z
    unsigned short* __restrict__ out1,       // y1
    int M, const int* __restrict__ flagp)
{
  constexpr int K  = 256;
  constexpr int KB = 64;
  constexpr int KP = KB + 8;   // 72
  __shared__ __align__(16) unsigned short lW[2 * 128 * KP];

  const int fl   = *flagp;
  const int tid  = threadIdx.x;
  const int lane = tid & 63;
  const int wav  = tid >> 6;
  const int l16  = lane & 15;
  const int quad = lane >> 4;
  const int rowBase = blockIdx.x * 128 + wav * 32;

  f32x4 acc[2][2][8];
#pragma unroll
  for (int p = 0; p < 2; ++p)
#pragma unroll
    for (int s = 0; s < 2; ++s)
#pragma unroll
      for (int nt = 0; nt < 8; ++nt) acc[p][s][nt] = (f32x4){0.f, 0.f, 0.f, 0.f};

  for (int kb = 0; kb < K; kb += KB){
    __syncthreads();
#pragma unroll
    for (int i = tid; i < 2048; i += 256){
      int p = i >> 10, rem = i & 1023;
      int n = rem >> 3, c = rem & 7;
      const unsigned short* W = p ? WT1 : WT0;
      *(short8*)&lW[(p * 128 + n) * KP + c * 8] = *(const short8*)&W[n * K + kb + c * 8];
    }
    __syncthreads();
#pragma unroll
    for (int k0 = 0; k0 < KB; k0 += 32){
      short8 aF[2];
#pragma unroll
      for (int s = 0; s < 2; ++s){
        int r = rowBase + s * 16 + l16;
        short8 v = {};
        if (r < M){
          long off = (long)r * K + kb + k0 + quad * 8;
          if (fl){
            const float* Af = (const float*)A + off;
            f32x4 p0 = *(const f32x4*)Af;
            f32x4 p1 = *(const f32x4*)(Af + 4);
            v[0] = (short)f2bf(p0[0]); v[1] = (short)f2bf(p0[1]);
            v[2] = (short)f2bf(p0[2]); v[3] = (short)f2bf(p0[3]);
            v[4] = (short)f2bf(p1[0]); v[5] = (short)f2bf(p1[1]);
            v[6] = (short)f2bf(p1[2]); v[7] = (short)f2bf(p1[3]);
          } else {
            v = *(const short8*)((const unsigned short*)A + off);
          }
        }
        aF[s] = v;
      }
#pragma unroll
      for (int p = 0; p < 2; ++p)
#pragma unroll
        for (int nt = 0; nt < 8; ++nt){
          short8 bF = *(const short8*)&lW[(p * 128 + nt * 16 + l16) * KP + k0 + quad * 8];
          acc[p][0][nt] = __builtin_amdgcn_mfma_f32_16x16x32_bf16(aF[0], bF, acc[p][0][nt], 0, 0, 0);
          acc[p][1][nt] = __builtin_amdgcn_mfma_f32_16x16x32_bf16(aF[1], bF, acc[p][1][nt], 0, 0, 0);
        }
    }
  }

#pragma unroll
  for (int s = 0; s < 2; ++s){
    int r0 = rowBase + s * 16 + quad * 4;
#pragma unroll
    for (int nt = 0; nt < 8; ++nt){
      int col = nt * 16 + l16;
      float bv = bias0 ? ldf(bias0, col, fl) : 0.0f;
#pragma unroll
      for (int rg = 0; rg < 4; ++rg){
        int r = r0 + rg;
        if (r < M){
          out0[(long)r * 128 + col] = f2bf(acc[0][s][nt][rg] + bv);
          out1[(long)r * 128 + col] = f2bf(acc[1][s][nt][rg]);
        }
      }
    }
  }
}

// ---- single GEMM (for y2 = x1 @ W2, K=128, bf16 A) ----
template<int K>
__global__ __launch_bounds__(256) void gemm_bf16(
    const unsigned short* __restrict__ A,
    const unsigned short* __restrict__ WT,
    unsigned short* __restrict__ out, int M)
{
  constexpr int KB = 128;
  constexpr int KP = KB + 8;
  __shared__ __align__(16) unsigned short lW[128 * KP];

  const int tid  = threadIdx.x;
  const int lane = tid & 63;
  const int wav  = tid >> 6;
  const int l16  = lane & 15;
  const int quad = lane >> 4;
  const int rowBase = blockIdx.x * 128 + wav * 32;

  f32x4 acc[2][8];
#pragma unroll
  for (int s = 0; s < 2; ++s)
#pragma unroll
    for (int nt = 0; nt < 8; ++nt) acc[s][nt] = (f32x4){0.f, 0.f, 0.f, 0.f};

  for (int kb = 0; kb < K; kb += KB){
    __syncthreads();
#pragma unroll
    for (int i = tid; i < 128 * KB / 8; i += 256){
      int n = i >> 4, c = i & 15;
      *(short8*)&lW[n * KP + c * 8] = *(const short8*)&WT[n * K + kb + c * 8];
    }
    __syncthreads();
#pragma unroll
    for (int k0 = 0; k0 < KB; k0 += 32){
      short8 aF[2];
#pragma unroll
      for (int s = 0; s < 2; ++s){
        int r = rowBase + s * 16 + l16;
        short8 v = {};
        if (r < M) v = *(const short8*)&A[(long)r * K + kb + k0 + quad * 8];
        aF[s] = v;
      }
#pragma unroll
      for (int nt = 0; nt < 8; ++nt){
        short8 bF = *(const short8*)&lW[(nt * 16 + l16) * KP + k0 + quad * 8];
        acc[0][nt] = __builtin_amdgcn_mfma_f32_16x16x32_bf16(aF[0], bF, acc[0][nt], 0, 0, 0);
        acc[1][nt] = __builtin_amdgcn_mfma_f32_16x16x32_bf16(aF[1], bF, acc[1][nt], 0, 0, 0);
      }
    }
  }

#pragma unroll
  for (int s = 0; s < 2; ++s){
    int r0 = rowBase + s * 16 + quad * 4;
#pragma unroll
    for (int nt = 0; nt < 8; ++nt){
      int col = nt * 16 + l16;
#pragma unroll
      for (int rg = 0; rg < 4; ++rg){
        int r = r0 + rg;
        if (r < M) out[(long)r * 128 + col] = f2bf(acc[s][nt][rg]);
      }
    }
  }
}

// ---- row gather core: lane = (eslot: L>>4, fgrp: L&15), dwordx4 gathers ----
// 4 edges per load instruction, 16 edges in flight per unrolled group.
__device__ __forceinline__ void row_gather8(
    int e0, int e1, const int* __restrict__ cols, const void* __restrict__ vals,
    const unsigned short* __restrict__ Y, int lane, int fl, float f[8])
{
  const int eslot = lane >> 4;
  const int fgrp  = lane & 15;
#pragma unroll
  for (int t = 0; t < 8; ++t) f[t] = 0.f;

  for (int ebase = e0; ebase < e1; ebase += 64){
    int cnt = e1 - ebase; if (cnt > 64) cnt = 64;
    int idx = ebase + lane;
    int cl = 0; float vl = 0.f;
    if (idx < e1){ cl = cols[idx]; vl = ldf(vals, idx, fl); }
    int nb4 = (cnt + 15) >> 4;   // groups of 16 edges (4 insts)
    for (int g = 0; g < nb4; ++g){
#pragma unroll
      for (int j = 0; j < 4; ++j){
        int myj = g * 16 + j * 4 + eslot;
        int   c = __shfl(cl, myj);
        float v = __shfl(vl, myj);
        if (myj >= cnt){ c = 0; v = 0.f; }   // padded edge: row 0, weight 0
        const uint4 q = *(const uint4*)&Y[(long)c * 128 + fgrp * 8];
        f[0] = fmaf(v, bf2f((unsigned short)(q.x & 0xffffu)), f[0]);
        f[1] = fmaf(v, bf2f((unsigned short)(q.x >> 16)),     f[1]);
        f[2] = fmaf(v, bf2f((unsigned short)(q.y & 0xffffu)), f[2]);
        f[3] = fmaf(v, bf2f((unsigned short)(q.y >> 16)),     f[3]);
        f[4] = fmaf(v, bf2f((unsigned short)(q.z & 0xffffu)), f[4]);
        f[5] = fmaf(v, bf2f((unsigned short)(q.z >> 16)),     f[5]);
        f[6] = fmaf(v, bf2f((unsigned short)(q.w & 0xffffu)), f[6]);
        f[7] = fmaf(v, bf2f((unsigned short)(q.w >> 16)),     f[7]);
      }
    }
  }
  // combine eslot quads: after this every lane holds totals for its fgrp
#pragma unroll
  for (int t = 0; t < 8; ++t){
    f[t] += __shfl_xor(f[t], 16);
    f[t] += __shfl_xor(f[t], 32);
  }
}

// ---- spmm1 fused: x1[r] = relu(spmm(y1)[r] + b1) + z[r], bf16 out ----
__global__ __launch_bounds__(256) void spmm1_f(
    const int* __restrict__ rs, const int* __restrict__ cols,
    const void* __restrict__ vals, const unsigned short* __restrict__ Y,
    const unsigned short* __restrict__ z, const void* __restrict__ b1,
    unsigned short* __restrict__ x1, int N, const int* __restrict__ flagp)
{
  const int fl   = *flagp;
  const int lane = threadIdx.x & 63;
  const int wav  = threadIdx.x >> 6;
  int r = blockIdx.x * 4 + wav;
  if (r >= N) return;
  int e0 = __builtin_amdgcn_readfirstlane(rs[r]);
  int e1 = __builtin_amdgcn_readfirstlane(rs[r + 1]);
  float f[8];
  row_gather8(e0, e1, cols, vals, Y, lane, fl, f);
  if (lane < 16){
    long o = (long)r * 128 + lane * 8;
    uint4 zz = *(const uint4*)&z[o];
    unsigned int zw[4] = {zz.x, zz.y, zz.z, zz.w};
    uint4 ov;
    unsigned int* ow = (unsigned int*)&ov;
#pragma unroll
    for (int h = 0; h < 4; ++h){
      float b0 = ldf(b1, lane * 8 + 2 * h,     fl);
      float b1v= ldf(b1, lane * 8 + 2 * h + 1, fl);
      float r0 = fmaxf(f[2 * h]     + b0,  0.f) + bf2f((unsigned short)(zw[h] & 0xffffu));
      float r1 = fmaxf(f[2 * h + 1] + b1v, 0.f) + bf2f((unsigned short)(zw[h] >> 16));
      ow[h] = (unsigned int)f2bf(r0) | ((unsigned int)f2bf(r1) << 16);
    }
    *(uint4*)&x1[o] = ov;
  }
}

// ---- spmm2 fused: out[r] = log_softmax(spmm(y2)[r] + b2), dtype per flag ----
__global__ __launch_bounds__(256) void spmm2_f(
    const int* __restrict__ rs, const int* __restrict__ cols,
    const void* __restrict__ vals, const unsigned short* __restrict__ Y,
    const void* __restrict__ b2, void* __restrict__ out, int N,
    const int* __restrict__ flagp)
{
  const int fl   = *flagp;
  const int lane = threadIdx.x & 63;
  const int wav  = threadIdx.x >> 6;
  const int fgrp = lane & 15;
  int r = blockIdx.x * 4 + wav;
  if (r >= N) return;
  int e0 = __builtin_amdgcn_readfirstlane(rs[r]);
  int e1 = __builtin_amdgcn_readfirstlane(rs[r + 1]);
  float f[8];
  row_gather8(e0, e1, cols, vals, Y, lane, fl, f);
  float v[8];
#pragma unroll
  for (int t = 0; t < 8; ++t) v[t] = f[t] + ldf(b2, fgrp * 8 + t, fl);
  float m = v[0];
#pragma unroll
  for (int t = 1; t < 8; ++t) m = fmaxf(m, v[t]);
#pragma unroll
  for (int off = 1; off <= 8; off <<= 1) m = fmaxf(m, __shfl_xor(m, off));
  float s = 0.f;
#pragma unroll
  for (int t = 0; t < 8; ++t) s += expf(v[t] - m);
#pragma unroll
  for (int off = 1; off <= 8; off <<= 1) s += __shfl_xor(s, off);
  float lse = m + logf(s);
  if (lane < 16){
    long o = (long)r * 128 + fgrp * 8;
    if (fl){
      float4 w0, w1;
      w0.x = v[0]-lse; w0.y = v[1]-lse; w0.z = v[2]-lse; w0.w = v[3]-lse;
      w1.x = v[4]-lse; w1.y = v[5]-lse; w1.z = v[6]-lse; w1.w = v[7]-lse;
      *(float4*)&((float*)out)[o]     = w0;
      *(float4*)&((float*)out)[o + 4] = w1;
    } else {
      uint4 ov; unsigned int* ow = (unsigned int*)&ov;
#pragma unroll
      for (int h = 0; h < 4; ++h)
        ow[h] = (unsigned int)f2bf(v[2*h]-lse) | ((unsigned int)f2bf(v[2*h+1]-lse) << 16);
      *(uint4*)&((unsigned short*)out)[o] = ov;
    }
  }
}

extern "C" void kernel_launch(void* const* d_in, const int* in_sizes, int n_in,
                              void* d_out, int out_size, void* d_ws, size_t ws_size,
                              hipStream_t stream)
{
  const void* x    = d_in[0];
  const int*  erow = (const int*)d_in[1];
  const int*  ecol = (const int*)d_in[2];
  const void* eval = d_in[3];
  const void* Wres = d_in[4];
  const void* bres = d_in[5];
  const void* W1   = d_in[6];
  const void* b1   = d_in[7];
  const void* W2   = d_in[8];
  const void* b2   = d_in[9];
  const int N = in_sizes[0] / 256;   // 100000
  const int E = in_sizes[1];         // 1600000

  char* ws = (char*)d_ws;
  size_t szB = (size_t)N * 128 * 2;  // one bf16 [N,128] plane (25.6 MB)
  unsigned short* bufA  = (unsigned short*)ws;            // y1, then y2
  unsigned short* bufC  = (unsigned short*)(ws + szB);    // x1
  unsigned short* WresT = (unsigned short*)(ws + 2 * szB);
  unsigned short* W1T   = WresT + 256 * 128;
  unsigned short* W2T   = W1T   + 256 * 128;
  int*            flag  = (int*)(W2T + 256 * 128);
  int*            rs    = flag + 4;                        // [N+1] row_ptr
  unsigned short* zbuf  = (unsigned short*)d_out;          // z (bf16) in d_out

  detect<<<1, 256, 0, stream>>>((const unsigned short*)x, flag);
  wtrans<<<128, 256, 0, stream>>>(Wres, WresT, 256, flag);
  wtrans<<<128, 256, 0, stream>>>(W1,   W1T,   256, flag);
  wtrans<<< 64, 256, 0, stream>>>(W2,   W2T,   128, flag);
  rowptr_k<<<(E + 255) / 256, 256, 0, stream>>>(erow, rs, E, N);

  const int gBlocks = (N + 127) / 128;
  const int rBlocks = (N + 3) / 4;

  gemm_dual<<<gBlocks, 256, 0, stream>>>(x, WresT, W1T, bres, zbuf, bufA, N, flag); // z, y1

  spmm1_f<<<rBlocks, 256, 0, stream>>>(rs, ecol, eval, bufA, zbuf, b1, bufC, N, flag); // x1

  gemm_bf16<128><<<gBlocks, 256, 0, stream>>>(bufC, W2T, bufA, N);                     // y2

  spmm2_f<<<rBlocks, 256, 0, stream>>>(rs, ecol, eval, bufA, b2, d_out, N, flag);      // out
}

// Round 5
// 485.790 us; speedup vs baseline: 1.0004x; 1.0004x over previous
//
#include <hip/hip_runtime.h>

typedef __attribute__((ext_vector_type(8))) short short8;
typedef __attribute__((ext_vector_type(4))) float f32x4;

__device__ __forceinline__ float bf2f(unsigned short u){
  return __uint_as_float(((unsigned int)u) << 16);
}
__device__ __forceinline__ unsigned short f2bf(float f){
  unsigned int u = __float_as_uint(f);
  u += 0x7fffu + ((u >> 16) & 1u);   // RNE
  return (unsigned short)(u >> 16);
}
// dtype-dispatching scalar load: isF32 ? f32[i] : bf16[i]
__device__ __forceinline__ float ldf(const void* p, long i, int isF32){
  return isF32 ? ((const float*)p)[i] : bf2f(((const unsigned short*)p)[i]);
}

// ---- detect input dtype: bf16 (flag=0) vs f32 (flag=1) ----
__global__ void detect(const unsigned short* __restrict__ x, int* __restrict__ flag){
  __shared__ int s;
  if (threadIdx.x == 0) s = 0;
  __syncthreads();
  int bad = 0;
  for (int i = threadIdx.x; i < 2048; i += 256){
    unsigned int e = ((unsigned int)x[2 * i] >> 7) & 0xffu;
    if (e >= 0xF0u) bad = 1;
  }
  if (bad) atomicOr(&s, 1);
  __syncthreads();
  if (threadIdx.x == 0) *flag = s;
}

// ---- transpose W [K][128] -> WT [128][K], output canonical bf16 ----
__global__ void wtrans(const void* __restrict__ W, unsigned short* __restrict__ WT,
                       int K, const int* __restrict__ flag){
  int isF32 = *flag;
  int idx = blockIdx.x * 256 + threadIdx.x;
  if (idx >= K * 128) return;
  int n = idx / K, k = idx - n * K;
  WT[idx] = f2bf(ldf(W, (long)k * 128 + n, isF32));
}

// ---- row_ptr from sorted rows: rs[r] = first edge with row >= r ----
__global__ void rowptr_k(const int* __restrict__ rows, int* __restrict__ rs,
                         int E, int N){
  int e = blockIdx.x * 256 + threadIdx.x;
  if (e >= E) return;
  if (e == 0){
    for (int r = 0; r <= rows[0]; ++r) rs[r] = 0;
  } else {
    int a = rows[e - 1], b = rows[e];
    for (int r = a + 1; r <= b; ++r) rs[r] = e;
  }
  if (e == E - 1){
    for (int r = rows[E - 1] + 1; r <= N; ++r) rs[r] = E;
  }
}

// ---- A-fragment load (one 16B MFMA A-operand), dtype per fl ----
__device__ __forceinline__ short8 loadA_frag(const void* __restrict__ A, int r,
                                             int M, int K, int kk, int fl){
  short8 v = {};
  if (r < M){
    long off = (long)r * K + kk;
    if (fl){
      const float* Af = (const float*)A + off;
      f32x4 p0 = *(const f32x4*)Af;
      f32x4 p1 = *(const f32x4*)(Af + 4);
      v[0] = (short)f2bf(p0[0]); v[1] = (short)f2bf(p0[1]);
      v[2] = (short)f2bf(p0[2]); v[3] = (short)f2bf(p0[3]);
      v[4] = (short)f2bf(p1[0]); v[5] = (short)f2bf(p1[1]);
      v[6] = (short)f2bf(p1[2]); v[7] = (short)f2bf(p1[3]);
    } else {
      v = *(const short8*)((const unsigned short*)A + off);
    }
  }
  return v;
}

// ---- fused dual GEMM: z = A@W0 + b0, y1 = A@W1 (K=256), bf16 out ----
// 256 thr / 4 waves, M-tile 64: waves 0-1 -> z strips 0-1, waves 2-3 -> y1.
// acc[2][8] = 64 AGPR/wave (occupancy 3 waves/SIMD, vs 128-AGPR cliff in r4).
// KB=64 W-chunks (both W in 36 KB LDS); A frags prefetched across barriers.
__global__ __launch_bounds__(256) void gemm_fused(
    const void* __restrict__ A,
    const unsigned short* __restrict__ WT0,  // [128][256] bf16
    const unsigned short* __restrict__ WT1,  // [128][256] bf16
    const void* __restrict__ bias0,
    unsigned short* __restrict__ out0,       // z
    unsigned short* __restrict__ out1,       // y1
    int M, const int* __restrict__ flagp)
{
  constexpr int K  = 256;
  constexpr int KB = 64;
  constexpr int KP = KB + 8;   // 72
  __shared__ __align__(16) unsigned short lW[2 * 128 * KP];

  const int fl    = *flagp;
  const int tid   = threadIdx.x;
  const int lane  = tid & 63;
  const int wv    = tid >> 6;
  const int p     = wv >> 1;          // 0: z, 1: y1
  const int strip = wv & 1;
  const int l16   = lane & 15;
  const int quad  = lane >> 4;
  const int rowBase = blockIdx.x * 64 + strip * 32;
  unsigned short* outp = p ? out1 : out0;

  f32x4 acc[2][8];
#pragma unroll
  for (int s = 0; s < 2; ++s)
#pragma unroll
    for (int nt = 0; nt < 8; ++nt) acc[s][nt] = (f32x4){0.f, 0.f, 0.f, 0.f};

  // prefetch first A fragments (k = quad*8)
  short8 pre0 = loadA_frag(A, rowBase + l16,      M, K, quad * 8, fl);
  short8 pre1 = loadA_frag(A, rowBase + 16 + l16, M, K, quad * 8, fl);

  for (int kb = 0; kb < K; kb += KB){
    __syncthreads();
#pragma unroll
    for (int i = tid; i < 2048; i += 256){
      int pp = i >> 10, rem = i & 1023;
      int n = rem >> 3, c = rem & 7;
      const unsigned short* W = pp ? WT1 : WT0;
      *(short8*)&lW[(pp * 128 + n) * KP + c * 8] = *(const short8*)&W[n * K + kb + c * 8];
    }
    __syncthreads();
#pragma unroll
    for (int k0 = 0; k0 < KB; k0 += 32){
      short8 aF0 = pre0, aF1 = pre1;
      int nk = kb + k0 + 32;
      if (nk < K){   // prefetch next k-step (crosses next barrier harmlessly)
        pre0 = loadA_frag(A, rowBase + l16,      M, K, nk + quad * 8, fl);
        pre1 = loadA_frag(A, rowBase + 16 + l16, M, K, nk + quad * 8, fl);
      }
#pragma unroll
      for (int nt = 0; nt < 8; ++nt){
        short8 bF = *(const short8*)&lW[(p * 128 + nt * 16 + l16) * KP + k0 + quad * 8];
        acc[0][nt] = __builtin_amdgcn_mfma_f32_16x16x32_bf16(aF0, bF, acc[0][nt], 0, 0, 0);
        acc[1][nt] = __builtin_amdgcn_mfma_f32_16x16x32_bf16(aF1, bF, acc[1][nt], 0, 0, 0);
      }
    }
  }

#pragma unroll
  for (int s = 0; s < 2; ++s){
    int r0 = rowBase + s * 16 + quad * 4;
#pragma unroll
    for (int nt = 0; nt < 8; ++nt){
      int col = nt * 16 + l16;
      float bv = (p == 0) ? ldf(bias0, col, fl) : 0.0f;
#pragma unroll
      for (int rg = 0; rg < 4; ++rg){
        int r = r0 + rg;
        if (r < M) outp[(long)r * 128 + col] = f2bf(acc[s][nt][rg] + bv);
      }
    }
  }
}

// ---- y2 = x1 @ W2 (K=128, bf16 A): full-K W in LDS, single barrier ----
__global__ __launch_bounds__(256) void gemm_y2(
    const unsigned short* __restrict__ A,
    const unsigned short* __restrict__ WT,   // [128][128] bf16
    unsigned short* __restrict__ out, int M)
{
  constexpr int K  = 128;
  constexpr int KP = K + 8;
  __shared__ __align__(16) unsigned short lW[128 * KP];

  const int tid  = threadIdx.x;
  const int lane = tid & 63;
  const int wav  = tid >> 6;
  const int l16  = lane & 15;
  const int quad = lane >> 4;
  const int rowBase = blockIdx.x * 128 + wav * 32;

  // prefetch first A fragments before staging (overlap with LDS writes)
  short8 pre0 = loadA_frag(A, rowBase + l16,      M, K, quad * 8, 0);
  short8 pre1 = loadA_frag(A, rowBase + 16 + l16, M, K, quad * 8, 0);

#pragma unroll
  for (int i = tid; i < 2048; i += 256){
    int n = i >> 4, c = i & 15;
    *(short8*)&lW[n * KP + c * 8] = *(const short8*)&WT[n * K + c * 8];
  }
  __syncthreads();

  f32x4 acc[2][8];
#pragma unroll
  for (int s = 0; s < 2; ++s)
#pragma unroll
    for (int nt = 0; nt < 8; ++nt) acc[s][nt] = (f32x4){0.f, 0.f, 0.f, 0.f};

#pragma unroll
  for (int k0 = 0; k0 < K; k0 += 32){
    short8 aF0 = pre0, aF1 = pre1;
    if (k0 + 32 < K){
      pre0 = loadA_frag(A, rowBase + l16,      M, K, k0 + 32 + quad * 8, 0);
      pre1 = loadA_frag(A, rowBase + 16 + l16, M, K, k0 + 32 + quad * 8, 0);
    }
#pragma unroll
    for (int nt = 0; nt < 8; ++nt){
      short8 bF = *(const short8*)&lW[(nt * 16 + l16) * KP + k0 + quad * 8];
      acc[0][nt] = __builtin_amdgcn_mfma_f32_16x16x32_bf16(aF0, bF, acc[0][nt], 0, 0, 0);
      acc[1][nt] = __builtin_amdgcn_mfma_f32_16x16x32_bf16(aF1, bF, acc[1][nt], 0, 0, 0);
    }
  }

#pragma unroll
  for (int s = 0; s < 2; ++s){
    int r0 = rowBase + s * 16 + quad * 4;
#pragma unroll
    for (int nt = 0; nt < 8; ++nt){
      int col = nt * 16 + l16;
#pragma unroll
      for (int rg = 0; rg < 4; ++rg){
        int r = r0 + rg;
        if (r < M) out[(long)r * 128 + col] = f2bf(acc[s][nt][rg]);
      }
    }
  }
}

// ---- row gather core: lane = (eslot: L>>4, fgrp: L&15), dwordx4 gathers ----
__device__ __forceinline__ void row_gather8(
    int e0, int e1, const int* __restrict__ cols, const void* __restrict__ vals,
    const unsigned short* __restrict__ Y, int lane, int fl, float f[8])
{
  const int eslot = lane >> 4;
  const int fgrp  = lane & 15;
#pragma unroll
  for (int t = 0; t < 8; ++t) f[t] = 0.f;

  for (int ebase = e0; ebase < e1; ebase += 64){
    int cnt = e1 - ebase; if (cnt > 64) cnt = 64;
    int idx = ebase + lane;
    int cl = 0; float vl = 0.f;
    if (idx < e1){ cl = cols[idx]; vl = ldf(vals, idx, fl); }
    int nb4 = (cnt + 15) >> 4;
    for (int g = 0; g < nb4; ++g){
#pragma unroll
      for (int j = 0; j < 4; ++j){
        int myj = g * 16 + j * 4 + eslot;
        int   c = __shfl(cl, myj);
        float v = __shfl(vl, myj);
        if (myj >= cnt){ c = 0; v = 0.f; }
        const uint4 q = *(const uint4*)&Y[(long)c * 128 + fgrp * 8];
        f[0] = fmaf(v, bf2f((unsigned short)(q.x & 0xffffu)), f[0]);
        f[1] = fmaf(v, bf2f((unsigned short)(q.x >> 16)),     f[1]);
        f[2] = fmaf(v, bf2f((unsigned short)(q.y & 0xffffu)), f[2]);
        f[3] = fmaf(v, bf2f((unsigned short)(q.y >> 16)),     f[3]);
        f[4] = fmaf(v, bf2f((unsigned short)(q.z & 0xffffu)), f[4]);
        f[5] = fmaf(v, bf2f((unsigned short)(q.z >> 16)),     f[5]);
        f[6] = fmaf(v, bf2f((unsigned short)(q.w & 0xffffu)), f[6]);
        f[7] = fmaf(v, bf2f((unsigned short)(q.w >> 16)),     f[7]);
      }
    }
  }
#pragma unroll
  for (int t = 0; t < 8; ++t){
    f[t] += __shfl_xor(f[t], 16);
    f[t] += __shfl_xor(f[t], 32);
  }
}

// ---- spmm1 fused: x1[r] = relu(spmm(y1)[r] + b1) + z[r], bf16 out ----
__global__ __launch_bounds__(256) void spmm1_f(
    const int* __restrict__ rs, const int* __restrict__ cols,
    const void* __restrict__ vals, const unsigned short* __restrict__ Y,
    const unsigned short* __restrict__ z, const void* __restrict__ b1,
    unsigned short* __restrict__ x1, int N, const int* __restrict__ flagp)
{
  const int fl   = *flagp;
  const int lane = threadIdx.x & 63;
  const int wav  = threadIdx.x >> 6;
  int r = blockIdx.x * 4 + wav;
  if (r >= N) return;
  int e0 = __builtin_amdgcn_readfirstlane(rs[r]);
  int e1 = __builtin_amdgcn_readfirstlane(rs[r + 1]);
  float f[8];
  row_gather8(e0, e1, cols, vals, Y, lane, fl, f);
  if (lane < 16){
    long o = (long)r * 128 + lane * 8;
    uint4 zz = *(const uint4*)&z[o];
    unsigned int zw[4] = {zz.x, zz.y, zz.z, zz.w};
    uint4 ov;
    unsigned int* ow = (unsigned int*)&ov;
#pragma unroll
    for (int h = 0; h < 4; ++h){
      float b0 = ldf(b1, lane * 8 + 2 * h,     fl);
      float b1v= ldf(b1, lane * 8 + 2 * h + 1, fl);
      float r0 = fmaxf(f[2 * h]     + b0,  0.f) + bf2f((unsigned short)(zw[h] & 0xffffu));
      float r1 = fmaxf(f[2 * h + 1] + b1v, 0.f) + bf2f((unsigned short)(zw[h] >> 16));
      ow[h] = (unsigned int)f2bf(r0) | ((unsigned int)f2bf(r1) << 16);
    }
    *(uint4*)&x1[o] = ov;
  }
}

// ---- spmm2 fused: out[r] = log_softmax(spmm(y2)[r] + b2), dtype per flag ----
__global__ __launch_bounds__(256) void spmm2_f(
    const int* __restrict__ rs, const int* __restrict__ cols,
    const void* __restrict__ vals, const unsigned short* __restrict__ Y,
    const void* __restrict__ b2, void* __restrict__ out, int N,
    const int* __restrict__ flagp)
{
  const int fl   = *flagp;
  const int lane = threadIdx.x & 63;
  const int wav  = threadIdx.x >> 6;
  const int fgrp = lane & 15;
  int r = blockIdx.x * 4 + wav;
  if (r >= N) return;
  int e0 = __builtin_amdgcn_readfirstlane(rs[r]);
  int e1 = __builtin_amdgcn_readfirstlane(rs[r + 1]);
  float f[8];
  row_gather8(e0, e1, cols, vals, Y, lane, fl, f);
  float v[8];
#pragma unroll
  for (int t = 0; t < 8; ++t) v[t] = f[t] + ldf(b2, fgrp * 8 + t, fl);
  float m = v[0];
#pragma unroll
  for (int t = 1; t < 8; ++t) m = fmaxf(m, v[t]);
#pragma unroll
  for (int off = 1; off <= 8; off <<= 1) m = fmaxf(m, __shfl_xor(m, off));
  float s = 0.f;
#pragma unroll
  for (int t = 0; t < 8; ++t) s += expf(v[t] - m);
#pragma unroll
  for (int off = 1; off <= 8; off <<= 1) s += __shfl_xor(s, off);
  float lse = m + logf(s);
  if (lane < 16){
    long o = (long)r * 128 + fgrp * 8;
    if (fl){
      float4 w0, w1;
      w0.x = v[0]-lse; w0.y = v[1]-lse; w0.z = v[2]-lse; w0.w = v[3]-lse;
      w1.x = v[4]-lse; w1.y = v[5]-lse; w1.z = v[6]-lse; w1.w = v[7]-lse;
      *(float4*)&((float*)out)[o]     = w0;
      *(float4*)&((float*)out)[o + 4] = w1;
    } else {
      uint4 ov; unsigned int* ow = (unsigned int*)&ov;
#pragma unroll
      for (int h = 0; h < 4; ++h)
        ow[h] = (unsigned int)f2bf(v[2*h]-lse) | ((unsigned int)f2bf(v[2*h+1]-lse) << 16);
      *(uint4*)&((unsigned short*)out)[o] = ov;
    }
  }
}

extern "C" void kernel_launch(void* const* d_in, const int* in_sizes, int n_in,
                              void* d_out, int out_size, void* d_ws, size_t ws_size,
                              hipStream_t stream)
{
  const void* x    = d_in[0];
  const int*  erow = (const int*)d_in[1];
  const int*  ecol = (const int*)d_in[2];
  const void* eval = d_in[3];
  const void* Wres = d_in[4];
  const void* bres = d_in[5];
  const void* W1   = d_in[6];
  const void* b1   = d_in[7];
  const void* W2   = d_in[8];
  const void* b2   = d_in[9];
  const int N = in_sizes[0] / 256;   // 100000
  const int E = in_sizes[1];         // 1600000

  char* ws = (char*)d_ws;
  size_t szB = (size_t)N * 128 * 2;  // one bf16 [N,128] plane (25.6 MB)
  unsigned short* bufA  = (unsigned short*)ws;            // y1, then y2
  unsigned short* bufC  = (unsigned short*)(ws + szB);    // x1
  unsigned short* WresT = (unsigned short*)(ws + 2 * szB);
  unsigned short* W1T   = WresT + 256 * 128;
  unsigned short* W2T   = W1T   + 256 * 128;
  int*            flag  = (int*)(W2T + 256 * 128);
  int*            rs    = flag + 4;                        // [N+1] row_ptr
  unsigned short* zbuf  = (unsigned short*)d_out;          // z (bf16) in d_out

  detect<<<1, 256, 0, stream>>>((const unsigned short*)x, flag);
  wtrans<<<128, 256, 0, stream>>>(Wres, WresT, 256, flag);
  wtrans<<<128, 256, 0, stream>>>(W1,   W1T,   256, flag);
  wtrans<<< 64, 256, 0, stream>>>(W2,   W2T,   128, flag);
  rowptr_k<<<(E + 255) / 256, 256, 0, stream>>>(erow, rs, E, N);

  const int fBlocks = (N + 63) / 64;     // M-tile 64 for gemm_fused
  const int gBlocks = (N + 127) / 128;   // M-tile 128 for gemm_y2
  const int rBlocks = (N + 3) / 4;

  gemm_fused<<<fBlocks, 256, 0, stream>>>(x, WresT, W1T, bres, zbuf, bufA, N, flag); // z, y1

  spmm1_f<<<rBlocks, 256, 0, stream>>>(rs, ecol, eval, bufA, zbuf, b1, bufC, N, flag); // x1

  gemm_y2<<<gBlocks, 256, 0, stream>>>(bufC, W2T, bufA, N);                            // y2

  spmm2_f<<<rBlocks, 256, 0, stream>>>(rs, ecol, eval, bufA, b2, d_out, N, flag);      // out
}